// Round 2
// baseline (98.793 us; speedup 1.0000x reference)
//
#include <hip/hip_runtime.h>

// ReflectionRayTracer: 8192 rays x 2048 quad surfaces. out[ray][surf] = t*mask.
//
// R8: DISCRIMINATING PROBE — identical kernels to R7, but trace_kernel is
// launched TWICE (idempotent: reads o/dr/cf, writes identical values to the
// same addresses; output bit-identical to R6/R7).
//
// Why: R7 halved per-pair VALU issue + store instructions => NULL delta. So
// trace is not issue-bound. R5->R6 (NT->plain stores) was a win => store path
// matters. Leading theory: trace time = memory-system write drain (own 64 MiB
// + poison backlog), instruction-independent. The marginal cost of the second
// launch discriminates:
//   - drain-bound:  2nd pass rewrites its own dirty L3 lines, no new HBM
//     bytes => M ~ 8-14 us  => dur ~ 94-100 us
//   - latency/structure-bound: 2nd pass repeats full cost => M ~ 30-40 us
//     => dur ~ 115-125 us
// This round is expected to REGRESS dur_us; it buys the number that decides
// whether the remaining ~25-40 us of non-fill time is attackable.

#define N_RAYS 8192
#define N_SURF 2048
constexpr int RPB = 16;   // rays per block
constexpr int SPT = 2;    // surfaces per thread

typedef float v2f __attribute__((ext_vector_type(2)));
#define FMA2(a, b, c) __builtin_elementwise_fma((a), (b), (c))

__device__ __forceinline__ float safef(float x) {
    return (x == 0.0f) ? 1e-18f : x;   // jnp.where(x==0, EPS, x)
}

// ---- kernel 1: per-surface coefficients, SoA cf[13][N_SURF] ----
__global__ __launch_bounds__(256) void coeff_kernel(
    const float* __restrict__ V, float* __restrict__ cf)
{
    const int s = blockIdx.x * 256 + threadIdx.x;

    const float4 p0 = *(const float4*)(V + (size_t)s * 12);
    const float4 p1 = *(const float4*)(V + (size_t)s * 12 + 4);
    const float4 p2 = *(const float4*)(V + (size_t)s * 12 + 8);
    const float ax = p0.x, ay = p0.y, az = p0.z;       // a = V[s][0]
    const float bx = p0.w, by = p1.x, bz = p1.y;       // b = V[s][1]
    const float cx = p1.z, cy = p1.w, cz = p2.x;       // c = V[s][2]
    const float wx = p2.y, wy = p2.z, wz = p2.w;       // V[s][3]

    // Plane: v = normalize(cross(b-a, c-a)); k = -dot(v, V[s][3])
    const float e0x = bx - ax, e0y = by - ay, e0z = bz - az;
    const float e1x = cx - ax, e1y = cy - ay, e1z = cz - az;
    const float nx = e0y * e1z - e0z * e1y;
    const float ny = e0z * e1x - e0x * e1z;
    const float nz = e0x * e1y - e0y * e1x;
    const float rn = __builtin_amdgcn_rsqf(fmaf(nx, nx, fmaf(ny, ny, nz * nz)));
    const float vx = nx * rn, vy = ny * rn, vz = nz * rn;
    const float k = -fmaf(vx, wx, fmaf(vy, wy, vz * wz));

    const float B  = ax * bz - az * bx;
    const float D  = ax * by - ay * bx;                 // G == D
    const float E  = ax * cz - az * cx;
    const float P  = ay * cx - ax * cy;
    const float F  = B * P;
    const float rden = __builtin_amdgcn_rcpf(safef(D * fmaf(E, D, F)));
    const float rD   = __builtin_amdgcn_rcpf(safef(D));
    const float rAX  = __builtin_amdgcn_rcpf(safef(ax));

    const float DB = D * B, DD = D * D;
    const float g0 = (DB * ay - DD * az) * rden;
    const float g1 = -(DB * ax) * rden;
    const float g2 = (DD * ax) * rden;
    const float bp  = P * rD;
    const float bb0 = fmaf(bp, g0, -ay * rD);
    const float bb1 = fmaf(bp, g1,  ax * rD);
    const float bb2 = bp * g2;
    const float ab = -bx * rAX, ac = -cx * rAX;
    const float aa0 = fmaf(ab, bb0, fmaf(ac, g0, rAX));
    const float aa1 = fmaf(ab, bb1, ac * g1);
    const float aa2 = fmaf(ab, bb2, ac * g2);

    cf[ 0 * N_SURF + s] = vx;
    cf[ 1 * N_SURF + s] = vy;
    cf[ 2 * N_SURF + s] = vz;
    cf[ 3 * N_SURF + s] = k;
    cf[ 4 * N_SURF + s] = g0;
    cf[ 5 * N_SURF + s] = g1;
    cf[ 6 * N_SURF + s] = g2;
    cf[ 7 * N_SURF + s] = bb0;
    cf[ 8 * N_SURF + s] = bb1;
    cf[ 9 * N_SURF + s] = bb2;
    cf[10 * N_SURF + s] = aa0;
    cf[11 * N_SURF + s] = aa1;
    cf[12 * N_SURF + s] = aa2;
}

// ---- kernel 2: the ray x surface sweep, 2 surfaces/thread packed ----
__global__ __launch_bounds__(256, 8) void trace_kernel(
    const float* __restrict__ o, const float* __restrict__ dr,
    const float* __restrict__ cf, float* __restrict__ out)
{
    const int s0 = (blockIdx.x * 256 + threadIdx.x) * SPT;  // surface pair base

    const v2f vx  = *(const v2f*)(cf +  0 * N_SURF + s0);
    const v2f vy  = *(const v2f*)(cf +  1 * N_SURF + s0);
    const v2f vz  = *(const v2f*)(cf +  2 * N_SURF + s0);
    const v2f kk  = *(const v2f*)(cf +  3 * N_SURF + s0);
    const v2f g0  = *(const v2f*)(cf +  4 * N_SURF + s0);
    const v2f g1  = *(const v2f*)(cf +  5 * N_SURF + s0);
    const v2f g2  = *(const v2f*)(cf +  6 * N_SURF + s0);
    const v2f bb0 = *(const v2f*)(cf +  7 * N_SURF + s0);
    const v2f bb1 = *(const v2f*)(cf +  8 * N_SURF + s0);
    const v2f bb2 = *(const v2f*)(cf +  9 * N_SURF + s0);
    const v2f aa0 = *(const v2f*)(cf + 10 * N_SURF + s0);
    const v2f aa1 = *(const v2f*)(cf + 11 * N_SURF + s0);
    const v2f aa2 = *(const v2f*)(cf + 12 * N_SURF + s0);

    const int ray0 = blockIdx.y * RPB;
    float* outp = out + (size_t)ray0 * N_SURF + s0;

#pragma unroll 4
    for (int i = 0; i < RPB; ++i) {
        const int ray = ray0 + i;
        // Wave-uniform ray loads -> scalar (SMEM) loads.
        const float o0 = o[ray * 3 + 0], o1 = o[ray * 3 + 1], o2 = o[ray * 3 + 2];
        const float d0 = dr[ray * 3 + 0], d1 = dr[ray * 3 + 1], d2 = dr[ray * 3 + 2];
        const v2f o0v = o0, o1v = o1, o2v = o2;
        const v2f d0v = d0, d1v = d1, d2v = d2;

        const v2f vo_k = FMA2(o0v, vx, FMA2(o1v, vy, FMA2(o2v, vz, kk))); // k + v.o
        const v2f vd   = FMA2(d0v, vx, FMA2(d1v, vy, d2v * vz));
        v2f rv;
        rv.x = __builtin_amdgcn_rcpf(vd.x);
        rv.y = __builtin_amdgcn_rcpf(vd.y);
        const v2f t = -vo_k * rv;

        const v2f rx = FMA2(t, d0v, o0v);
        const v2f ry = FMA2(t, d1v, o1v);
        const v2f rz = FMA2(t, d2v, o2v);

        const v2f gam = FMA2(g0,  rx, FMA2(g1,  ry, g2  * rz));
        const v2f bet = FMA2(bb0, rx, FMA2(bb1, ry, bb2 * rz));
        const v2f alp = FMA2(aa0, rx, FMA2(aa1, ry, aa2 * rz));

        const float mnx = fminf(fminf(bet.x, gam.x), alp.x);  // v_min3_f32
        const float mny = fminf(fminf(bet.y, gam.y), alp.y);
        v2f res;
        res.x = (mnx > 0.0f) ? t.x : 0.0f;
        res.y = (mny > 0.0f) ? t.y : 0.0f;
        *(v2f*)(outp + (size_t)i * N_SURF) = res;   // global_store_dwordx2
    }
}

extern "C" void kernel_launch(void* const* d_in, const int* in_sizes, int n_in,
                              void* d_out, int out_size, void* d_ws, size_t ws_size,
                              hipStream_t stream) {
    const float* o  = (const float*)d_in[0];
    const float* dr = (const float*)d_in[1];
    const float* V  = (const float*)d_in[2];
    float* out = (float*)d_out;
    float* cf  = (float*)d_ws;   // 13 * 2048 * 4 B = 106 KiB

    coeff_kernel<<<dim3(N_SURF / 256), dim3(256), 0, stream>>>(V, cf);

    // PROBE: launch the sweep twice. Idempotent => output unchanged.
    // Marginal cost of the 2nd launch = trace's structure-bound component.
    trace_kernel<<<dim3(N_SURF / (256 * SPT), N_RAYS / RPB), dim3(256), 0, stream>>>(o, dr, cf, out);
    trace_kernel<<<dim3(N_SURF / (256 * SPT), N_RAYS / RPB), dim3(256), 0, stream>>>(o, dr, cf, out);
}

// Round 3
// 85.415 us; speedup vs baseline: 1.1566x; 1.1566x over previous
//
#include <hip/hip_runtime.h>

// ReflectionRayTracer: 8192 rays x 2048 quad surfaces. out[ray][surf] = t*mask.
//
// R9: LINEARIZE THE STORE STREAM.
//  Evidence: R8 probe — 2nd identical sweep costs only 12.6us (vs ~40us for
//  the 1st). Trace1 is paced by victim evictions: each store allocates an L3
//  line, evicting dirty poison to HBM. Old grid emitted 512B chunks strided
//  8KB from 2048 interleaved blocks => eviction stream scattered => ~2.8TB/s
//  effective HBM write (matches R5's NT measurement). Fix:
//   - 1024-thread block = one full output row (SPT=2, 2048 surfaces).
//   - Each block owns 32 CONSECUTIVE rays => writes a 256KB contiguous span
//     in address order. Grid = 256 blocks = 1/CU, 4 waves/SIMD.
//   - Evictions now leave L3 near-sequentially => ~6TB/s like the fill.
//  Coeff preamble back inline (drops R7's extra launch); amortized over 32
//  rows. Per-element math op-identical to R6/R7 => absmax 2.578125 unchanged.

#define N_RAYS 8192
#define N_SURF 2048
constexpr int RPB = 32;    // rays (rows) per block
constexpr int SPT = 2;     // surfaces per thread
constexpr int TPB = 1024;  // threads per block: TPB*SPT == N_SURF (full row)

typedef float v2f __attribute__((ext_vector_type(2)));
#define FMA2(a, b, c) __builtin_elementwise_fma((a), (b), (c))

__device__ __forceinline__ float safef(float x) {
    return (x == 0.0f) ? 1e-18f : x;   // jnp.where(x==0, EPS, x)
}

// Per-surface coefficients (identical formula sequence to R6/R7).
__device__ __forceinline__ void surf_coeffs(const float* __restrict__ V, int s,
                                            float* __restrict__ c)
{
    const float4 p0 = *(const float4*)(V + (size_t)s * 12);
    const float4 p1 = *(const float4*)(V + (size_t)s * 12 + 4);
    const float4 p2 = *(const float4*)(V + (size_t)s * 12 + 8);
    const float ax = p0.x, ay = p0.y, az = p0.z;       // a = V[s][0]
    const float bx = p0.w, by = p1.x, bz = p1.y;       // b = V[s][1]
    const float cx = p1.z, cy = p1.w, cz = p2.x;       // c = V[s][2]
    const float wx = p2.y, wy = p2.z, wz = p2.w;       // V[s][3]

    // Plane: v = normalize(cross(b-a, c-a)); k = -dot(v, V[s][3])
    const float e0x = bx - ax, e0y = by - ay, e0z = bz - az;
    const float e1x = cx - ax, e1y = cy - ay, e1z = cz - az;
    const float nx = e0y * e1z - e0z * e1y;
    const float ny = e0z * e1x - e0x * e1z;
    const float nz = e0x * e1y - e0y * e1x;
    const float rn = __builtin_amdgcn_rsqf(fmaf(nx, nx, fmaf(ny, ny, nz * nz)));
    const float vx = nx * rn, vy = ny * rn, vz = nz * rn;
    const float k = -fmaf(vx, wx, fmaf(vy, wy, vz * wz));

    const float B  = ax * bz - az * bx;
    const float D  = ax * by - ay * bx;                 // G == D
    const float E  = ax * cz - az * cx;
    const float P  = ay * cx - ax * cy;
    const float F  = B * P;
    const float rden = __builtin_amdgcn_rcpf(safef(D * fmaf(E, D, F)));
    const float rD   = __builtin_amdgcn_rcpf(safef(D));
    const float rAX  = __builtin_amdgcn_rcpf(safef(ax));

    const float DB = D * B, DD = D * D;
    const float g0 = (DB * ay - DD * az) * rden;
    const float g1 = -(DB * ax) * rden;
    const float g2 = (DD * ax) * rden;
    const float bp  = P * rD;
    const float bb0 = fmaf(bp, g0, -ay * rD);
    const float bb1 = fmaf(bp, g1,  ax * rD);
    const float bb2 = bp * g2;
    const float ab = -bx * rAX, ac = -cx * rAX;
    const float aa0 = fmaf(ab, bb0, fmaf(ac, g0, rAX));
    const float aa1 = fmaf(ab, bb1, ac * g1);
    const float aa2 = fmaf(ab, bb2, ac * g2);

    c[0] = vx;  c[1] = vy;  c[2] = vz;  c[3] = k;
    c[4] = g0;  c[5] = g1;  c[6] = g2;
    c[7] = bb0; c[8] = bb1; c[9] = bb2;
    c[10] = aa0; c[11] = aa1; c[12] = aa2;
}

__global__ __launch_bounds__(TPB, 4) void trace_kernel(
    const float* __restrict__ o, const float* __restrict__ dr,
    const float* __restrict__ V, float* __restrict__ out)
{
    const int s0 = threadIdx.x * SPT;   // surface pair within the row

    // ---- inline preamble: coeffs for 2 adjacent surfaces, packed v2f ----
    float cA[13], cB[13];
    surf_coeffs(V, s0, cA);
    surf_coeffs(V, s0 + 1, cB);
    const v2f vx  = {cA[0],  cB[0]};
    const v2f vy  = {cA[1],  cB[1]};
    const v2f vz  = {cA[2],  cB[2]};
    const v2f kk  = {cA[3],  cB[3]};
    const v2f g0  = {cA[4],  cB[4]};
    const v2f g1  = {cA[5],  cB[5]};
    const v2f g2  = {cA[6],  cB[6]};
    const v2f bb0 = {cA[7],  cB[7]};
    const v2f bb1 = {cA[8],  cB[8]};
    const v2f bb2 = {cA[9],  cB[9]};
    const v2f aa0 = {cA[10], cB[10]};
    const v2f aa1 = {cA[11], cB[11]};
    const v2f aa2 = {cA[12], cB[12]};

    // ---- ray loop: block writes 32 consecutive rows = 256KB linear span ----
    const int ray0 = blockIdx.x * RPB;
    float* outp = out + (size_t)ray0 * N_SURF + s0;

#pragma unroll 4
    for (int i = 0; i < RPB; ++i) {
        const int ray = ray0 + i;
        // Wave-uniform ray loads -> scalar (SMEM) loads.
        const float o0 = o[ray * 3 + 0], o1 = o[ray * 3 + 1], o2 = o[ray * 3 + 2];
        const float d0 = dr[ray * 3 + 0], d1 = dr[ray * 3 + 1], d2 = dr[ray * 3 + 2];
        const v2f o0v = o0, o1v = o1, o2v = o2;
        const v2f d0v = d0, d1v = d1, d2v = d2;

        const v2f vo_k = FMA2(o0v, vx, FMA2(o1v, vy, FMA2(o2v, vz, kk))); // k + v.o
        const v2f vd   = FMA2(d0v, vx, FMA2(d1v, vy, d2v * vz));
        v2f rv;
        rv.x = __builtin_amdgcn_rcpf(vd.x);
        rv.y = __builtin_amdgcn_rcpf(vd.y);
        const v2f t = -vo_k * rv;

        const v2f rx = FMA2(t, d0v, o0v);
        const v2f ry = FMA2(t, d1v, o1v);
        const v2f rz = FMA2(t, d2v, o2v);

        const v2f gam = FMA2(g0,  rx, FMA2(g1,  ry, g2  * rz));
        const v2f bet = FMA2(bb0, rx, FMA2(bb1, ry, bb2 * rz));
        const v2f alp = FMA2(aa0, rx, FMA2(aa1, ry, aa2 * rz));

        const float mnx = fminf(fminf(bet.x, gam.x), alp.x);  // v_min3_f32
        const float mny = fminf(fminf(bet.y, gam.y), alp.y);
        v2f res;
        res.x = (mnx > 0.0f) ? t.x : 0.0f;
        res.y = (mny > 0.0f) ? t.y : 0.0f;
        *(v2f*)(outp + (size_t)i * N_SURF) = res;   // row-linear dwordx2 store
    }
}

extern "C" void kernel_launch(void* const* d_in, const int* in_sizes, int n_in,
                              void* d_out, int out_size, void* d_ws, size_t ws_size,
                              hipStream_t stream) {
    const float* o  = (const float*)d_in[0];
    const float* dr = (const float*)d_in[1];
    const float* V  = (const float*)d_in[2];
    float* out = (float*)d_out;

    trace_kernel<<<dim3(N_RAYS / RPB), dim3(TPB), 0, stream>>>(o, dr, V, out);
}

// Round 4
// 83.174 us; speedup vs baseline: 1.1878x; 1.0269x over previous
//
#include <hip/hip_runtime.h>

// ReflectionRayTracer: 8192 rays x 2048 quad surfaces. out[ray][surf] = t*mask.
//
// R10: R9 + NON-TEMPORAL stores (single change).
//  Ledger: R7 (fewer instructions) null; R9 (linear store order) null; R8
//  probe: warm re-run of the sweep costs only 12.6us (= 64MiB @ ~5.3TB/s,
//  the write roofline) vs ~40us cold. The ~27us cold penalty is therefore
//  ALLOCATION-state cost: the harness poison leaves all 256MiB of L3 dirty,
//  so launch-1 stores must evict a dirty victim per line allocated (plus
//  possible read-for-ownership), ~128MiB forced HBM traffic.
//  Fix: __builtin_nontemporal_store => no-allocate path, no victims, no RFO.
//  R5's NT regression was on the SCATTERED pattern (512B chunks / 8KB stride
//  from 2048 interleaved blocks, ~2.8TB/s). R9's layout is 256 contiguous
//  256KB spans — the linear pattern NT handles at near-peak. This completes
//  the {writeback,NT} x {scattered,linear} 2x2 (the fourth cell).
//  Math untouched => absmax 4.03125 (R9 values).

#define N_RAYS 8192
#define N_SURF 2048
constexpr int RPB = 32;    // rays (rows) per block
constexpr int SPT = 2;     // surfaces per thread
constexpr int TPB = 1024;  // threads per block: TPB*SPT == N_SURF (full row)

typedef float v2f __attribute__((ext_vector_type(2)));
#define FMA2(a, b, c) __builtin_elementwise_fma((a), (b), (c))

__device__ __forceinline__ float safef(float x) {
    return (x == 0.0f) ? 1e-18f : x;   // jnp.where(x==0, EPS, x)
}

// Per-surface coefficients (identical formula sequence to R9).
__device__ __forceinline__ void surf_coeffs(const float* __restrict__ V, int s,
                                            float* __restrict__ c)
{
    const float4 p0 = *(const float4*)(V + (size_t)s * 12);
    const float4 p1 = *(const float4*)(V + (size_t)s * 12 + 4);
    const float4 p2 = *(const float4*)(V + (size_t)s * 12 + 8);
    const float ax = p0.x, ay = p0.y, az = p0.z;       // a = V[s][0]
    const float bx = p0.w, by = p1.x, bz = p1.y;       // b = V[s][1]
    const float cx = p1.z, cy = p1.w, cz = p2.x;       // c = V[s][2]
    const float wx = p2.y, wy = p2.z, wz = p2.w;       // V[s][3]

    // Plane: v = normalize(cross(b-a, c-a)); k = -dot(v, V[s][3])
    const float e0x = bx - ax, e0y = by - ay, e0z = bz - az;
    const float e1x = cx - ax, e1y = cy - ay, e1z = cz - az;
    const float nx = e0y * e1z - e0z * e1y;
    const float ny = e0z * e1x - e0x * e1z;
    const float nz = e0x * e1y - e0y * e1x;
    const float rn = __builtin_amdgcn_rsqf(fmaf(nx, nx, fmaf(ny, ny, nz * nz)));
    const float vx = nx * rn, vy = ny * rn, vz = nz * rn;
    const float k = -fmaf(vx, wx, fmaf(vy, wy, vz * wz));

    const float B  = ax * bz - az * bx;
    const float D  = ax * by - ay * bx;                 // G == D
    const float E  = ax * cz - az * cx;
    const float P  = ay * cx - ax * cy;
    const float F  = B * P;
    const float rden = __builtin_amdgcn_rcpf(safef(D * fmaf(E, D, F)));
    const float rD   = __builtin_amdgcn_rcpf(safef(D));
    const float rAX  = __builtin_amdgcn_rcpf(safef(ax));

    const float DB = D * B, DD = D * D;
    const float g0 = (DB * ay - DD * az) * rden;
    const float g1 = -(DB * ax) * rden;
    const float g2 = (DD * ax) * rden;
    const float bp  = P * rD;
    const float bb0 = fmaf(bp, g0, -ay * rD);
    const float bb1 = fmaf(bp, g1,  ax * rD);
    const float bb2 = bp * g2;
    const float ab = -bx * rAX, ac = -cx * rAX;
    const float aa0 = fmaf(ab, bb0, fmaf(ac, g0, rAX));
    const float aa1 = fmaf(ab, bb1, ac * g1);
    const float aa2 = fmaf(ab, bb2, ac * g2);

    c[0] = vx;  c[1] = vy;  c[2] = vz;  c[3] = k;
    c[4] = g0;  c[5] = g1;  c[6] = g2;
    c[7] = bb0; c[8] = bb1; c[9] = bb2;
    c[10] = aa0; c[11] = aa1; c[12] = aa2;
}

__global__ __launch_bounds__(TPB, 4) void trace_kernel(
    const float* __restrict__ o, const float* __restrict__ dr,
    const float* __restrict__ V, float* __restrict__ out)
{
    const int s0 = threadIdx.x * SPT;   // surface pair within the row

    // ---- inline preamble: coeffs for 2 adjacent surfaces, packed v2f ----
    float cA[13], cB[13];
    surf_coeffs(V, s0, cA);
    surf_coeffs(V, s0 + 1, cB);
    const v2f vx  = {cA[0],  cB[0]};
    const v2f vy  = {cA[1],  cB[1]};
    const v2f vz  = {cA[2],  cB[2]};
    const v2f kk  = {cA[3],  cB[3]};
    const v2f g0  = {cA[4],  cB[4]};
    const v2f g1  = {cA[5],  cB[5]};
    const v2f g2  = {cA[6],  cB[6]};
    const v2f bb0 = {cA[7],  cB[7]};
    const v2f bb1 = {cA[8],  cB[8]};
    const v2f bb2 = {cA[9],  cB[9]};
    const v2f aa0 = {cA[10], cB[10]};
    const v2f aa1 = {cA[11], cB[11]};
    const v2f aa2 = {cA[12], cB[12]};

    // ---- ray loop: block writes 32 consecutive rows = 256KB linear span ----
    const int ray0 = blockIdx.x * RPB;
    float* outp = out + (size_t)ray0 * N_SURF + s0;

#pragma unroll 4
    for (int i = 0; i < RPB; ++i) {
        const int ray = ray0 + i;
        // Wave-uniform ray loads -> scalar (SMEM) loads.
        const float o0 = o[ray * 3 + 0], o1 = o[ray * 3 + 1], o2 = o[ray * 3 + 2];
        const float d0 = dr[ray * 3 + 0], d1 = dr[ray * 3 + 1], d2 = dr[ray * 3 + 2];
        const v2f o0v = o0, o1v = o1, o2v = o2;
        const v2f d0v = d0, d1v = d1, d2v = d2;

        const v2f vo_k = FMA2(o0v, vx, FMA2(o1v, vy, FMA2(o2v, vz, kk))); // k + v.o
        const v2f vd   = FMA2(d0v, vx, FMA2(d1v, vy, d2v * vz));
        v2f rv;
        rv.x = __builtin_amdgcn_rcpf(vd.x);
        rv.y = __builtin_amdgcn_rcpf(vd.y);
        const v2f t = -vo_k * rv;

        const v2f rx = FMA2(t, d0v, o0v);
        const v2f ry = FMA2(t, d1v, o1v);
        const v2f rz = FMA2(t, d2v, o2v);

        const v2f gam = FMA2(g0,  rx, FMA2(g1,  ry, g2  * rz));
        const v2f bet = FMA2(bb0, rx, FMA2(bb1, ry, bb2 * rz));
        const v2f alp = FMA2(aa0, rx, FMA2(aa1, ry, aa2 * rz));

        const float mnx = fminf(fminf(bet.x, gam.x), alp.x);  // v_min3_f32
        const float mny = fminf(fminf(bet.y, gam.y), alp.y);
        v2f res;
        res.x = (mnx > 0.0f) ? t.x : 0.0f;
        res.y = (mny > 0.0f) ? t.y : 0.0f;
        // NT store: no-allocate => no victim eviction / RFO against the
        // full-dirty poison cache. Linear 256KB spans => near-peak HBM write.
        __builtin_nontemporal_store(res, (v2f*)(outp + (size_t)i * N_SURF));
    }
}

extern "C" void kernel_launch(void* const* d_in, const int* in_sizes, int n_in,
                              void* d_out, int out_size, void* d_ws, size_t ws_size,
                              hipStream_t stream) {
    const float* o  = (const float*)d_in[0];
    const float* dr = (const float*)d_in[1];
    const float* V  = (const float*)d_in[2];
    float* out = (float*)d_out;

    trace_kernel<<<dim3(N_RAYS / RPB), dim3(TPB), 0, stream>>>(o, dr, V, out);
}

// Round 6
// 82.237 us; speedup vs baseline: 1.2013x; 1.0114x over previous
//
#include <hip/hip_runtime.h>

// ReflectionRayTracer: 8192 rays x 2048 quad surfaces. out[ray][surf] = t*mask.
//
// R11b: RETRY of R11 (previous round died on container acquisition, not on
// the kernel — no compile/pytest error was produced). Single change vs R10:
// stores issued via inline asm with the FULL cache-policy bit set:
//   global_store_dwordx2 vaddr, vdata, off sc0 sc1 nt
//  Why: R8 proved the cold/warm gap is allocation-state (warm rerun 12.6us vs
//  cold ~40us). R9 (ordering) null, R10 (__builtin_nontemporal_store) only
//  -2us => the builtin emits just the nt hint, not a no-allocate path.
//  sc0+sc1 = system-scope store (coherent by definition — fabric handles any
//  resident stale copies, so no poison-writeback hazard) and with nt selects
//  the streaming write path. Wave stores cover 4 full 128B lines, blocks
//  write 256KB linear spans => pure full-line streams, no RFO.
//  Math untouched => absmax 4.03125 (R9/R10 values).

#define N_RAYS 8192
#define N_SURF 2048
constexpr int RPB = 32;    // rays (rows) per block
constexpr int SPT = 2;     // surfaces per thread
constexpr int TPB = 1024;  // threads per block: TPB*SPT == N_SURF (full row)

typedef float v2f __attribute__((ext_vector_type(2)));
#define FMA2(a, b, c) __builtin_elementwise_fma((a), (b), (c))

__device__ __forceinline__ float safef(float x) {
    return (x == 0.0f) ? 1e-18f : x;   // jnp.where(x==0, EPS, x)
}

// Per-surface coefficients (identical formula sequence to R9/R10).
__device__ __forceinline__ void surf_coeffs(const float* __restrict__ V, int s,
                                            float* __restrict__ c)
{
    const float4 p0 = *(const float4*)(V + (size_t)s * 12);
    const float4 p1 = *(const float4*)(V + (size_t)s * 12 + 4);
    const float4 p2 = *(const float4*)(V + (size_t)s * 12 + 8);
    const float ax = p0.x, ay = p0.y, az = p0.z;       // a = V[s][0]
    const float bx = p0.w, by = p1.x, bz = p1.y;       // b = V[s][1]
    const float cx = p1.z, cy = p1.w, cz = p2.x;       // c = V[s][2]
    const float wx = p2.y, wy = p2.z, wz = p2.w;       // V[s][3]

    // Plane: v = normalize(cross(b-a, c-a)); k = -dot(v, V[s][3])
    const float e0x = bx - ax, e0y = by - ay, e0z = bz - az;
    const float e1x = cx - ax, e1y = cy - ay, e1z = cz - az;
    const float nx = e0y * e1z - e0z * e1y;
    const float ny = e0z * e1x - e0x * e1z;
    const float nz = e0x * e1y - e0y * e1x;
    const float rn = __builtin_amdgcn_rsqf(fmaf(nx, nx, fmaf(ny, ny, nz * nz)));
    const float vx = nx * rn, vy = ny * rn, vz = nz * rn;
    const float k = -fmaf(vx, wx, fmaf(vy, wy, vz * wz));

    const float B  = ax * bz - az * bx;
    const float D  = ax * by - ay * bx;                 // G == D
    const float E  = ax * cz - az * cx;
    const float P  = ay * cx - ax * cy;
    const float F  = B * P;
    const float rden = __builtin_amdgcn_rcpf(safef(D * fmaf(E, D, F)));
    const float rD   = __builtin_amdgcn_rcpf(safef(D));
    const float rAX  = __builtin_amdgcn_rcpf(safef(ax));

    const float DB = D * B, DD = D * D;
    const float g0 = (DB * ay - DD * az) * rden;
    const float g1 = -(DB * ax) * rden;
    const float g2 = (DD * ax) * rden;
    const float bp  = P * rD;
    const float bb0 = fmaf(bp, g0, -ay * rD);
    const float bb1 = fmaf(bp, g1,  ax * rD);
    const float bb2 = bp * g2;
    const float ab = -bx * rAX, ac = -cx * rAX;
    const float aa0 = fmaf(ab, bb0, fmaf(ac, g0, rAX));
    const float aa1 = fmaf(ab, bb1, ac * g1);
    const float aa2 = fmaf(ab, bb2, ac * g2);

    c[0] = vx;  c[1] = vy;  c[2] = vz;  c[3] = k;
    c[4] = g0;  c[5] = g1;  c[6] = g2;
    c[7] = bb0; c[8] = bb1; c[9] = bb2;
    c[10] = aa0; c[11] = aa1; c[12] = aa2;
}

__global__ __launch_bounds__(TPB, 4) void trace_kernel(
    const float* __restrict__ o, const float* __restrict__ dr,
    const float* __restrict__ V, float* __restrict__ out)
{
    const int s0 = threadIdx.x * SPT;   // surface pair within the row

    // ---- inline preamble: coeffs for 2 adjacent surfaces, packed v2f ----
    float cA[13], cB[13];
    surf_coeffs(V, s0, cA);
    surf_coeffs(V, s0 + 1, cB);
    const v2f vx  = {cA[0],  cB[0]};
    const v2f vy  = {cA[1],  cB[1]};
    const v2f vz  = {cA[2],  cB[2]};
    const v2f kk  = {cA[3],  cB[3]};
    const v2f g0  = {cA[4],  cB[4]};
    const v2f g1  = {cA[5],  cB[5]};
    const v2f g2  = {cA[6],  cB[6]};
    const v2f bb0 = {cA[7],  cB[7]};
    const v2f bb1 = {cA[8],  cB[8]};
    const v2f bb2 = {cA[9],  cB[9]};
    const v2f aa0 = {cA[10], cB[10]};
    const v2f aa1 = {cA[11], cB[11]};
    const v2f aa2 = {cA[12], cB[12]};

    // ---- ray loop: block writes 32 consecutive rows = 256KB linear span ----
    const int ray0 = blockIdx.x * RPB;
    float* outp = out + (size_t)ray0 * N_SURF + s0;

#pragma unroll 4
    for (int i = 0; i < RPB; ++i) {
        const int ray = ray0 + i;
        // Wave-uniform ray loads -> scalar (SMEM) loads.
        const float o0 = o[ray * 3 + 0], o1 = o[ray * 3 + 1], o2 = o[ray * 3 + 2];
        const float d0 = dr[ray * 3 + 0], d1 = dr[ray * 3 + 1], d2 = dr[ray * 3 + 2];
        const v2f o0v = o0, o1v = o1, o2v = o2;
        const v2f d0v = d0, d1v = d1, d2v = d2;

        const v2f vo_k = FMA2(o0v, vx, FMA2(o1v, vy, FMA2(o2v, vz, kk))); // k + v.o
        const v2f vd   = FMA2(d0v, vx, FMA2(d1v, vy, d2v * vz));
        v2f rv;
        rv.x = __builtin_amdgcn_rcpf(vd.x);
        rv.y = __builtin_amdgcn_rcpf(vd.y);
        const v2f t = -vo_k * rv;

        const v2f rx = FMA2(t, d0v, o0v);
        const v2f ry = FMA2(t, d1v, o1v);
        const v2f rz = FMA2(t, d2v, o2v);

        const v2f gam = FMA2(g0,  rx, FMA2(g1,  ry, g2  * rz));
        const v2f bet = FMA2(bb0, rx, FMA2(bb1, ry, bb2 * rz));
        const v2f alp = FMA2(aa0, rx, FMA2(aa1, ry, aa2 * rz));

        const float mnx = fminf(fminf(bet.x, gam.x), alp.x);  // v_min3_f32
        const float mny = fminf(fminf(bet.y, gam.y), alp.y);
        v2f res;
        res.x = (mnx > 0.0f) ? t.x : 0.0f;
        res.y = (mny > 0.0f) ? t.y : 0.0f;

        // Streaming store: system-scope + non-temporal => no-allocate write
        // path, no victim eviction against the full-dirty poison cache.
        v2f* p = (v2f*)(outp + (size_t)i * N_SURF);
        asm volatile("global_store_dwordx2 %0, %1, off sc0 sc1 nt"
                     :: "v"(p), "v"(res) : "memory");
    }
}

extern "C" void kernel_launch(void* const* d_in, const int* in_sizes, int n_in,
                              void* d_out, int out_size, void* d_ws, size_t ws_size,
                              hipStream_t stream) {
    const float* o  = (const float*)d_in[0];
    const float* dr = (const float*)d_in[1];
    const float* V  = (const float*)d_in[2];
    float* out = (float*)d_out;

    trace_kernel<<<dim3(N_RAYS / RPB), dim3(TPB), 0, stream>>>(o, dr, V, out);
}